// Round 5
// baseline (269.939 us; speedup 1.0000x reference)
//
#include <hip/hip_runtime.h>
#include <hip/hip_bf16.h>
#include <stdint.h>

// ---------------------------------------------------------------------------
// SelfAttention2d: B=4, C=256, H=W=64 (N=4096), NUM_HEADS=4 (hd=64), GROUPS=8
// R16: flash_attn splits fragment traffic across pipes: K stays in LDS
//      (16 KB double-buffer, staged by DMA), V fragments are loaded DIRECTLY
//      from global (L2-resident: 2 bh per XCD = 2MB < 4MB XCD-L2) on the
//      separate TA/L1 pipe. This halves the serialized LDS-read pipe load
//      (R15: every wave re-reads 16KB/kt from LDS -> ~41us/CU; now ~20us)
//      and overlaps it with the V path. Unlike R13: small live set (~110
//      regs) and NO forced launch_bounds cap -> no spill. Key-split grid
//      1024 + attn_merge retained from R15. Other kernels frozen.
// ---------------------------------------------------------------------------

#define B_  4
#define C_  256
#define N_  4096
#define NH_ 4
#define HD_ 64
#define G_  8
#define CPG_ 32
#define GRP_ELEMS (CPG_ * N_)

typedef __attribute__((ext_vector_type(8))) short short8;
typedef __attribute__((ext_vector_type(4))) float f32x4;
typedef __attribute__((ext_vector_type(4))) unsigned short us4;

__device__ __forceinline__ unsigned short f2bf(float f) {
  union { float f; unsigned u; } v; v.f = f;
  unsigned r = v.u + 0x7FFFu + ((v.u >> 16) & 1u);
  return (unsigned short)(r >> 16);
}

// packed fp32x2 -> bf16x2 (v_cvt_pk_bf16_f32 on gfx950)
__device__ __forceinline__ unsigned pkbf2(float a, float b) {
  __hip_bfloat162 h = __float22bfloat162_rn(make_float2(a, b));
  unsigned r; __builtin_memcpy(&r, &h, sizeof(r)); return r;
}

// async 16B/lane global->LDS DMA; LDS dest = uniform base + lane*16
__device__ __forceinline__ void dma16(const unsigned short* g, unsigned short* l) {
  __builtin_amdgcn_global_load_lds(
      (const __attribute__((address_space(1))) unsigned int*)(g),
      (__attribute__((address_space(3))) unsigned int*)(l), 16, 0, 0);
}

// ---------------------------------------------------------------------------
// Kernel 1: gn_partial (blocks 0..511) + weight conversion (blocks 512..1279).
// ---------------------------------------------------------------------------
__global__ void gn_partial_cvt(const float* __restrict__ x, float* __restrict__ partial,
                               const float* __restrict__ qkvw, const float* __restrict__ projw,
                               unsigned short* __restrict__ wq, unsigned short* __restrict__ wp) {
  __shared__ float ls[8];
  int t = threadIdx.x;
  if (blockIdx.x >= 512) {
    int i = (blockIdx.x - 512) * 256 + t;
    if (i < 768 * 256) wq[i] = f2bf(qkvw[i]);
    if (i < 256 * 256) wp[i] = f2bf(projw[i]);
    return;
  }
  int idx = blockIdx.x;
  int slice = idx & 15, g = (idx >> 4) & 7, b = idx >> 7;
  const float* base = x + (size_t)(b * C_ + g * CPG_) * N_ + slice * 256;
  float s = 0.f, sq = 0.f;
#pragma unroll
  for (int cc = 0; cc < CPG_; cc++) {
    float v = base[(size_t)cc * N_ + t];
    s += v; sq += v * v;
  }
#pragma unroll
  for (int off = 32; off; off >>= 1) {
    s  += __shfl_down(s,  off, 64);
    sq += __shfl_down(sq, off, 64);
  }
  int wave = t >> 6, lane = t & 63;
  if (lane == 0) { ls[wave * 2] = s; ls[wave * 2 + 1] = sq; }
  __syncthreads();
  if (t == 0) {
    float S = ls[0] + ls[2] + ls[4] + ls[6];
    float SQ = ls[1] + ls[3] + ls[5] + ls[7];
    partial[idx * 2] = S; partial[idx * 2 + 1] = SQ;
  }
}

// ---------------------------------------------------------------------------
// Kernel 2: normalize + transpose with INLINE stats. x -> hT (B,N,C) bf16.
// ---------------------------------------------------------------------------
__global__ void gn_apply(const float* __restrict__ x,
                         const float* __restrict__ nw, const float* __restrict__ nb,
                         const float* __restrict__ partial, unsigned short* __restrict__ hT) {
  int nt = blockIdx.x, ct = blockIdx.y, b = blockIdx.z;
  __shared__ unsigned short tile[32][72];
  int t = threadIdx.x;
  int lane = t & 63;
  int grp = b * G_ + ct;
  float s = 0.f, sq = 0.f;
  if (lane < 16) {
    s  = partial[(grp * 16 + lane) * 2];
    sq = partial[(grp * 16 + lane) * 2 + 1];
  }
#pragma unroll
  for (int off = 8; off; off >>= 1) {
    s  += __shfl_down(s,  off, 64);
    sq += __shfl_down(sq, off, 64);
  }
  s  = __shfl(s,  0, 64);
  sq = __shfl(sq, 0, 64);
  const float inv = 1.0f / (float)GRP_ELEMS;
  float mean = s * inv;
  float rstd = rsqrtf(sq * inv - mean * mean + 1e-5f);

  int n_loc = t & 63, c_loc = t >> 6;
  const float* xb = x + (size_t)(b * C_ + ct * CPG_) * N_ + nt * 64;
#pragma unroll
  for (int rr = 0; rr < 8; rr++) {
    int cc = rr * 4 + c_loc;
    int c = ct * CPG_ + cc;
    float v = xb[(size_t)cc * N_ + n_loc];
    v = (v - mean) * rstd * nw[c] + nb[c];
    tile[cc][n_loc] = f2bf(v);
  }
  __syncthreads();
  // packed write: thread handles n = t>>2, 8 consecutive c = (t&3)*8
  int n = t >> 2, c8 = (t & 3) * 8;
  us4 lo, hi;
#pragma unroll
  for (int j = 0; j < 4; j++) lo[j] = tile[c8 + j][n];
#pragma unroll
  for (int j = 0; j < 4; j++) hi[j] = tile[c8 + 4 + j][n];
  unsigned short* outp = hT + ((size_t)(b * N_ + nt * 64 + n)) * C_ + ct * CPG_ + c8;
  *reinterpret_cast<us4*>(outp) = lo;
  *reinterpret_cast<us4*>(outp + 4) = hi;
}

// ---------------------------------------------------------------------------
// Kernel 3: qkv GEMM, 128-n x 128-o blocks. grid 768 (1D XCD-affine).
// ---------------------------------------------------------------------------
__global__ __launch_bounds__(256) void qkv_gemm(
    const unsigned short* __restrict__ hT, const unsigned short* __restrict__ wq,
    const float* __restrict__ qb,
    unsigned short* __restrict__ Qt, unsigned short* __restrict__ Kt,
    unsigned short* __restrict__ V) {
  int ot = blockIdx.x >> 7;
  int nt = (blockIdx.x & 127) >> 2;
  int b  = blockIdx.x & 3;
  int t = threadIdx.x;
  int wave = t >> 6, lane = t & 63, l15 = lane & 15, quad = lane >> 4, l7 = l15 & 7;

  __shared__ __align__(16) unsigned short sh[128 * C_];
  {
    int row0 = wave * 2 + (lane >> 5);
    int col8 = lane & 31;
    int src8 = (col8 & 24) | ((col8 & 7) ^ (row0 & 7));
    const unsigned short* gsrc = hT + ((size_t)(b * N_ + nt * 128 + row0)) * C_ + src8 * 8;
#pragma unroll
    for (int it = 0; it < 16; it++)
      dma16(gsrc + (size_t)it * 8 * C_, sh + (it * 8 + wave * 2) * C_);
  }

  f32x4 acc[2][8];
#pragma unroll
  for (int r = 0; r < 2; r++)
#pragma unroll
    for (int tt = 0; tt < 8; tt++) acc[r][tt] = (f32x4){0.f, 0.f, 0.f, 0.f};

  const short8* arow[2];
#pragma unroll
  for (int r = 0; r < 2; r++)
    arow[r] = reinterpret_cast<const short8*>(
        wq + (size_t)(ot * 128 + wave * 32 + r * 16 + l15) * C_);

  asm volatile("s_waitcnt vmcnt(0)" ::: "memory");
  __syncthreads();

#pragma unroll
  for (int kk = 0; kk < 8; kk++) {
    int g = kk * 4 + quad;
    int col8 = (g & 24) | ((g & 7) ^ l7);
    short8 bfr[8];
#pragma unroll
    for (int tt = 0; tt < 8; tt++)
      bfr[tt] = *reinterpret_cast<const short8*>(&sh[(tt * 16 + l15) * C_ + col8 * 8]);
#pragma unroll
    for (int r = 0; r < 2; r++) {
      short8 a = arow[r][g];
#pragma unroll
      for (int tt = 0; tt < 8; tt++)
        acc[r][tt] = __builtin_amdgcn_mfma_f32_16x16x32_bf16(a, bfr[tt], acc[r][tt], 0, 0, 0);
    }
  }

  int sec = ot >> 1;                       // 0=Q, 1=K, 2=V
  int head = (ot & 1) * 2 + (wave >> 1);   // head index within batch
  int bh = b * NH_ + head;
  const float SC = 0.125f * 1.44269504088896340736f;  // 1/sqrt(hd) * log2(e)

#pragma unroll
  for (int r = 0; r < 2; r++) {
    int o_glob = ot * 128 + wave * 32 + r * 16;        // row base (bias index)
    int cw = (o_glob & 63) + quad * 4;                 // channel within head
    if (sec == 0) {
#pragma unroll
      for (int tt = 0; tt < 8; tt++) {
        int n = nt * 128 + tt * 16 + l15;
        us4 pk;
#pragma unroll
        for (int i = 0; i < 4; i++)
          pk[i] = f2bf((acc[r][tt][i] + qb[o_glob + quad * 4 + i]) * SC);
        *reinterpret_cast<us4*>(Qt + ((size_t)bh * N_ + n) * HD_ + cw) = pk;
      }
    } else if (sec == 1) {
#pragma unroll
      for (int tt = 0; tt < 8; tt++) {
        int n = nt * 128 + tt * 16 + l15;
        us4 pk;
#pragma unroll
        for (int i = 0; i < 4; i++)
          pk[i] = f2bf(acc[r][tt][i] + qb[o_glob + quad * 4 + i]);
        *reinterpret_cast<us4*>(Kt + ((size_t)bh * N_ + n) * HD_ + cw) = pk;
      }
    } else {
#pragma unroll
      for (int tt = 0; tt < 8; tt++) {
        int n = nt * 128 + tt * 16 + l15;
#pragma unroll
        for (int i = 0; i < 4; i++)
          V[((size_t)bh * HD_ + cw + i) * N_ + n] =
              f2bf(acc[r][tt][i] + qb[o_glob + quad * 4 + i]);
      }
    }
  }
}

// ---------------------------------------------------------------------------
// Kernel 4: flash attention. R16: key-split grid 1024 = ks*512 + qt*16 + bh.
// K staged in LDS (16 KB dbuf); V fragments direct from global (L2-resident).
// Writes raw f32 O-partials + l-partials (merged by attn_merge).
// ---------------------------------------------------------------------------
__global__ __launch_bounds__(256, 2) void flash_attn(
    const unsigned short* __restrict__ Qt, const unsigned short* __restrict__ Kt,
    const unsigned short* __restrict__ Vv, float* __restrict__ Opart,
    float* __restrict__ lpart) {
  int bh = blockIdx.x & 15, qt = (blockIdx.x >> 4) & 31, ks = blockIdx.x >> 9;
  int b = bh >> 2, head = bh & 3;
  int t = threadIdx.x;
  int wave = t >> 6, lane = t & 63, l15 = lane & 15, quad = lane >> 4;
  int l7 = l15 & 7;

  const unsigned short* Qb = Qt + (size_t)bh * N_ * HD_;
  const unsigned short* Kb = Kt + (size_t)bh * N_ * HD_;
  const unsigned short* Vb = Vv + (size_t)bh * HD_ * N_;
  int q_base = qt * 128 + wave * 32;
  int k_base = ks * 2048;

  // K only: [buf][64 keys x 64 hd, 8-col-group XOR-swizzled] = 16384 B
  __shared__ __align__(16) unsigned short Ks[2][4096];

  const short8 vones = {(short)0x3F80, (short)0x3F80, (short)0x3F80, (short)0x3F80,
                        (short)0x3F80, (short)0x3F80, (short)0x3F80, (short)0x3F80};
  const f32x4 fzero = (f32x4){0.f, 0.f, 0.f, 0.f};

  short8 qf[2][2];
#pragma unroll
  for (int r = 0; r < 2; r++)
#pragma unroll
    for (int h = 0; h < 2; h++)
      qf[r][h] = *reinterpret_cast<const short8*>(
          Qb + (size_t)(q_base + r * 16 + l15) * HD_ + h * 32 + quad * 8);

  f32x4 oa[2][4], la[2];
#pragma unroll
  for (int r = 0; r < 2; r++) {
    la[r] = (f32x4){0.f, 0.f, 0.f, 0.f};
#pragma unroll
    for (int ct = 0; ct < 4; ct++) oa[r][ct] = (f32x4){0.f, 0.f, 0.f, 0.f};
  }

  int i8 = lane >> 3, e = lane & 7;
  int perm = (e ^ i8) * 8;   // XOR swizzle of 8-element groups
  // stage: 2 K DMAs/wave (rows-octet c = wave*2+cc)
  auto stage = [&](int kt2, int buf) {
    int m0 = k_base + kt2 * 64;
    unsigned short* Kd = &Ks[buf][0];
#pragma unroll
    for (int cc = 0; cc < 2; cc++) {
      int c = wave * 2 + cc;
      dma16(Kb + (size_t)(m0 + c * 8 + i8) * HD_ + perm, Kd + c * 512);
    }
  };

  stage(0, 0);

#pragma unroll 1
  for (int kt = 0; kt < 32; kt++) {
    int buf = kt & 1;
    int m0 = k_base + kt * 64;

    // V fragments straight from global (L2-resident; 16B contiguous/lane,
    // 64B per row segment). Issued first so QK+exp2 hides their latency.
    short8 vf[4][2];
#pragma unroll
    for (int ct = 0; ct < 4; ct++)
#pragma unroll
      for (int kh2 = 0; kh2 < 2; kh2++)
        vf[ct][kh2] = *reinterpret_cast<const short8*>(
            Vb + (size_t)(ct * 16 + l15) * N_ + m0 + (kh2 * 4 + quad) * 8);

    if (kt + 1 < 32) {
      stage(kt + 1, buf ^ 1);   // issue next K tile (2 DMAs)
      // newest 10 = 8 vf (this kt) + 2 next-K DMAs stay in flight; older
      // (this kt's K DMAs from prev iter) are drained.
      asm volatile("s_waitcnt vmcnt(10)" ::: "memory");
    } else {
      // newest 8 = this kt's vf; drains this kt's K DMAs.
      asm volatile("s_waitcnt vmcnt(8)" ::: "memory");
    }
    __builtin_amdgcn_s_barrier();

    const unsigned short* Kbuf = &Ks[buf][0];
    short8 kf[4][2];
#pragma unroll
    for (int tt = 0; tt < 4; tt++)
#pragma unroll
      for (int kh2 = 0; kh2 < 2; kh2++)
        kf[tt][kh2] = *reinterpret_cast<const short8*>(
            &Kbuf[(tt * 16 + l15) * 64 + (((kh2 * 4 + quad) ^ l7) * 8)]);

#pragma unroll
    for (int r = 0; r < 2; r++) {
      f32x4 s[4];
#pragma unroll
      for (int tt = 0; tt < 4; tt++) {
        f32x4 z = __builtin_amdgcn_mfma_f32_16x16x32_bf16(kf[tt][0], qf[r][0], fzero, 0, 0, 0);
        s[tt] = __builtin_amdgcn_mfma_f32_16x16x32_bf16(kf[tt][1], qf[r][1], z, 0, 0, 0);
      }
      // exp2 + pack: lane holds P[key=tt*16+quad*4+i][q=l15] as bf16x2 words.
      unsigned Apk[4], Bpk[4];
#pragma unroll
      for (int tt = 0; tt < 4; tt++) {
        Apk[tt] = pkbf2(__builtin_amdgcn_exp2f(s[tt][0]), __builtin_amdgcn_exp2f(s[tt][1]));
        Bpk[tt] = pkbf2(__builtin_amdgcn_exp2f(s[tt][2]), __builtin_amdgcn_exp2f(s[tt][3]));
      }
      // 4x4 quad transpose (fixed l15): PV B-frag lane (l15,quad) needs
      // P[key=quad*8+j][q=l15] -> permlane32_swap (quad^2) + permlane16_swap
      // (quad^1).
      union { unsigned u[4]; short8 v; } f0, f1;
      {
        auto ua = __builtin_amdgcn_permlane32_swap(Apk[0], Apk[1], false, false);
        auto pa = __builtin_amdgcn_permlane16_swap(ua[0], ua[1], false, false);
        auto ub = __builtin_amdgcn_permlane32_swap(Bpk[0], Bpk[1], false, false);
        auto pb = __builtin_amdgcn_permlane16_swap(ub[0], ub[1], false, false);
        f0.u[0] = pa[0]; f0.u[1] = pb[0]; f0.u[2] = pa[1]; f0.u[3] = pb[1];
        auto uc = __builtin_amdgcn_permlane32_swap(Apk[2], Apk[3], false, false);
        auto pc = __builtin_amdgcn_permlane16_swap(uc[0], uc[1], false, false);
        auto ud = __builtin_amdgcn_permlane32_swap(Bpk[2], Bpk[3], false, false);
        auto pd = __builtin_amdgcn_permlane16_swap(ud[0], ud[1], false, false);
        f1.u[0] = pc[0]; f1.u[1] = pd[0]; f1.u[2] = pc[1]; f1.u[3] = pd[1];
      }
      short8 pf0 = f0.v, pf1 = f1.v;
#pragma unroll
      for (int ct = 0; ct < 4; ct++) {
        oa[r][ct] = __builtin_amdgcn_mfma_f32_16x16x32_bf16(vf[ct][0], pf0, oa[r][ct], 0, 0, 0);
        oa[r][ct] = __builtin_amdgcn_mfma_f32_16x16x32_bf16(vf[ct][1], pf1, oa[r][ct], 0, 0, 0);
      }
      la[r] = __builtin_amdgcn_mfma_f32_16x16x32_bf16(vones, pf0, la[r], 0, 0, 0);
      la[r] = __builtin_amdgcn_mfma_f32_16x16x32_bf16(vones, pf1, la[r], 0, 0, 0);
    }
  }

  // ---- epilogue: write raw f32 partials (per key-half) ----
  float* Od = Opart + (size_t)ks * B_ * N_ * C_;
#pragma unroll
  for (int r = 0; r < 2; r++) {
    int n = q_base + r * 16 + l15;
#pragma unroll
    for (int ct = 0; ct < 4; ct++)
      *reinterpret_cast<f32x4*>(
          Od + ((size_t)(b * N_ + n)) * C_ + head * HD_ + ct * 16 + quad * 4) = oa[r][ct];
    if (quad == 0) lpart[(size_t)(ks * 16 + bh) * N_ + n] = la[r][0];
  }
}

// ---------------------------------------------------------------------------
// Kernel 4b: merge the two key-half partials -> aoT bf16.
// ---------------------------------------------------------------------------
__global__ __launch_bounds__(256) void attn_merge(
    const float* __restrict__ Opart, const float* __restrict__ lpart,
    unsigned short* __restrict__ aoT) {
  int g = blockIdx.x * 256 + threadIdx.x;
  int c4 = g & 63;                 // which 4-channel group within C
  int n  = (g >> 6) & (N_ - 1);
  int b  = g >> 18;
  int head = c4 >> 4;
  int bh = b * NH_ + head;
  size_t base = ((size_t)(b * N_ + n)) * C_ + c4 * 4;
  f32x4 p0 = *reinterpret_cast<const f32x4*>(Opart + base);
  f32x4 p1 = *reinterpret_cast<const f32x4*>(Opart + (size_t)B_ * N_ * C_ + base);
  float inv = 1.0f / (lpart[(size_t)bh * N_ + n] +
                      lpart[(size_t)(B_ * NH_ + bh) * N_ + n]);
  union { unsigned u2[2]; us4 v; } w;
  w.u2[0] = pkbf2((p0[0] + p1[0]) * inv, (p0[1] + p1[1]) * inv);
  w.u2[1] = pkbf2((p0[2] + p1[2]) * inv, (p0[3] + p1[3]) * inv);
  *reinterpret_cast<us4*>(aoT + base) = w.v;
}

// ---------------------------------------------------------------------------
// Kernel 5: proj GEMM + bias + residual, 128-n tiles, 1D XCD-aware grid
// (512 blocks): idx = ot*128 + nt*4 + b.
// ---------------------------------------------------------------------------
__global__ __launch_bounds__(256) void proj_gemm(
    const unsigned short* __restrict__ aoT, const unsigned short* __restrict__ wp,
    const float* __restrict__ pb, const float* __restrict__ x,
    float* __restrict__ out) {
  int ot = blockIdx.x >> 7;
  int nt = (blockIdx.x & 127) >> 2;
  int b  = blockIdx.x & 3;
  int t = threadIdx.x;
  int wave = t >> 6, lane = t & 63, l15 = lane & 15, quad = lane >> 4, l7 = l15 & 7;
  int o_base = ot * 64 + wave * 16;

  __shared__ __align__(16) unsigned short sh[128 * C_];
  {
    int row0 = wave * 2 + (lane >> 5);
    int col8 = lane & 31;
    int src8 = (col8 & 24) | ((col8 & 7) ^ (row0 & 7));
    const unsigned short* gsrc = aoT + ((size_t)(b * N_ + nt * 128 + row0)) * C_ + src8 * 8;
#pragma unroll
    for (int it = 0; it < 16; it++)
      dma16(gsrc + (size_t)it * 8 * C_, sh + (it * 8 + wave * 2) * C_);
  }

  f32x4 acc[8];
#pragma unroll
  for (int tt = 0; tt < 8; tt++) acc[tt] = (f32x4){0.f, 0.f, 0.f, 0.f};

  const short8* arow = reinterpret_cast<const short8*>(wp + (size_t)(o_base + l15) * C_);

  asm volatile("s_waitcnt vmcnt(0)" ::: "memory");
  __syncthreads();

#pragma unroll
  for (int kk = 0; kk < 8; kk++) {
    short8 a = arow[kk * 4 + quad];
    int g = kk * 4 + quad;
    int col8 = (g & 24) | ((g & 7) ^ l7);
#pragma unroll
    for (int tt = 0; tt < 8; tt++) {
      short8 bf = *reinterpret_cast<const short8*>(&sh[(tt * 16 + l15) * C_ + col8 * 8]);
      acc[tt] = __builtin_amdgcn_mfma_f32_16x16x32_bf16(a, bf, acc[tt], 0, 0, 0);
    }
  }
#pragma unroll
  for (int tt = 0; tt < 8; tt++) {
    int n = nt * 128 + tt * 16 + l15;
#pragma unroll
    for (int i = 0; i < 4; i++) {
      int o = o_base + quad * 4 + i;
      size_t idx = ((size_t)(b * C_ + o)) * N_ + n;
      out[idx] = acc[tt][i] + pb[o] + x[idx];
    }
  }
}

// ---------------------------------------------------------------------------
extern "C" void kernel_launch(void* const* d_in, const int* in_sizes, int n_in,
                              void* d_out, int out_size, void* d_ws, size_t ws_size,
                              hipStream_t stream) {
  const float* x      = (const float*)d_in[0];
  const float* norm_w = (const float*)d_in[1];
  const float* norm_b = (const float*)d_in[2];
  const float* qkv_w  = (const float*)d_in[3];
  const float* qkv_b  = (const float*)d_in[4];
  const float* proj_w = (const float*)d_in[5];
  const float* proj_b = (const float*)d_in[6];
  float* out = (float*)d_out;

  char* ws = (char*)d_ws;
  size_t off = 0;
  auto alloc = [&](size_t bytes) { size_t o = off; off = (off + bytes + 255) & ~(size_t)255; return o; };
  size_t off_partial = alloc(512 * 2 * sizeof(float));
  size_t off_stats   = alloc(32 * 2 * sizeof(float));   // unused (layout stability)
  size_t off_wq      = alloc((size_t)768 * 256 * 2);
  size_t off_wp      = alloc((size_t)256 * 256 * 2);
  size_t off_hT      = alloc((size_t)B_ * N_ * C_ * 2);
  size_t off_Qt      = alloc((size_t)B_ * NH_ * N_ * HD_ * 2);
  size_t off_Kt      = alloc((size_t)B_ * NH_ * N_ * HD_ * 2);
  size_t off_V       = alloc((size_t)B_ * NH_ * HD_ * N_ * 2);
  size_t off_aoT     = alloc((size_t)B_ * N_ * C_ * 2);
  size_t off_Opart   = alloc((size_t)2 * B_ * N_ * C_ * 4);      // 32 MB f32
  size_t off_lpart   = alloc((size_t)2 * B_ * NH_ * N_ * 4);     // 512 KB
  (void)off_stats;

  float* partial = (float*)(ws + off_partial);
  unsigned short* wq  = (unsigned short*)(ws + off_wq);
  unsigned short* wp  = (unsigned short*)(ws + off_wp);
  unsigned short* hT  = (unsigned short*)(ws + off_hT);
  unsigned short* Qt  = (unsigned short*)(ws + off_Qt);
  unsigned short* Kt  = (unsigned short*)(ws + off_Kt);
  unsigned short* V   = (unsigned short*)(ws + off_V);
  unsigned short* aoT = (unsigned short*)(ws + off_aoT);
  float* Opart = (float*)(ws + off_Opart);
  float* lpart = (float*)(ws + off_lpart);

  gn_partial_cvt<<<1280, 256, 0, stream>>>(x, partial, qkv_w, proj_w, wq, wp);
  gn_apply<<<dim3(64, 8, 4), 256, 0, stream>>>(x, norm_w, norm_b, partial, hT);
  qkv_gemm<<<768, 256, 0, stream>>>(hT, wq, qkv_b, Qt, Kt, V);
  flash_attn<<<1024, 256, 0, stream>>>(Qt, Kt, V, Opart, lpart);
  attn_merge<<<4096, 256, 0, stream>>>(Opart, lpart, aoT);
  proj_gemm<<<512, 256, 0, stream>>>(aoT, wp, proj_b, x, out);
}

// Round 6
// 184.418 us; speedup vs baseline: 1.4637x; 1.4637x over previous
//
#include <hip/hip_runtime.h>
#include <hip/hip_bf16.h>
#include <stdint.h>

// ---------------------------------------------------------------------------
// SelfAttention2d: B=4, C=256, H=W=64 (N=4096), NUM_HEADS=4 (hd=64), GROUPS=8
// R17: flash_attn reverted to the R12 structure (best measured: 93.0 us,
//      total 186.0): K+V staged in LDS per key-half (65 KB, dbuf), 4 waves =
//      2 qsub x 2 khalf, in-register P quad-transpose, cross-wave merge
//      epilogue. R13 (V-direct + forced occupancy cap) and R16 (V-direct)
//      both regressed: V-from-L2 exposes ~200-900 cy latency at low
//      occupancy; R15 (key-split) was neutral+merge-cost. R12's counters
//      show ~86% combined SIMD issue (VALU 52 + MFMA 34) => issue-bound.
//      New in R17: T5 s_setprio(1) across the compute phase (post-barrier
//      QK->exp2->permlane->PV), setprio(0) during staging issue — lets the
//      CU scheduler favor compute-phase waves over staging-phase waves
//      (attn-measured +4-7%, m191). Other kernels unchanged from R11.
// ---------------------------------------------------------------------------

#define B_  4
#define C_  256
#define N_  4096
#define NH_ 4
#define HD_ 64
#define G_  8
#define CPG_ 32
#define GRP_ELEMS (CPG_ * N_)

typedef __attribute__((ext_vector_type(8))) short short8;
typedef __attribute__((ext_vector_type(4))) float f32x4;
typedef __attribute__((ext_vector_type(4))) unsigned short us4;

__device__ __forceinline__ unsigned short f2bf(float f) {
  union { float f; unsigned u; } v; v.f = f;
  unsigned r = v.u + 0x7FFFu + ((v.u >> 16) & 1u);
  return (unsigned short)(r >> 16);
}

// packed fp32x2 -> bf16x2 (v_cvt_pk_bf16_f32 on gfx950)
__device__ __forceinline__ unsigned pkbf2(float a, float b) {
  __hip_bfloat162 h = __float22bfloat162_rn(make_float2(a, b));
  unsigned r; __builtin_memcpy(&r, &h, sizeof(r)); return r;
}

// async 16B/lane global->LDS DMA; LDS dest = uniform base + lane*16
__device__ __forceinline__ void dma16(const unsigned short* g, unsigned short* l) {
  __builtin_amdgcn_global_load_lds(
      (const __attribute__((address_space(1))) unsigned int*)(g),
      (__attribute__((address_space(3))) unsigned int*)(l), 16, 0, 0);
}

// ---------------------------------------------------------------------------
// Kernel 1: gn_partial (blocks 0..511) + weight conversion (blocks 512..1279).
// ---------------------------------------------------------------------------
__global__ void gn_partial_cvt(const float* __restrict__ x, float* __restrict__ partial,
                               const float* __restrict__ qkvw, const float* __restrict__ projw,
                               unsigned short* __restrict__ wq, unsigned short* __restrict__ wp) {
  __shared__ float ls[8];
  int t = threadIdx.x;
  if (blockIdx.x >= 512) {
    int i = (blockIdx.x - 512) * 256 + t;
    if (i < 768 * 256) wq[i] = f2bf(qkvw[i]);
    if (i < 256 * 256) wp[i] = f2bf(projw[i]);
    return;
  }
  int idx = blockIdx.x;
  int slice = idx & 15, g = (idx >> 4) & 7, b = idx >> 7;
  const float* base = x + (size_t)(b * C_ + g * CPG_) * N_ + slice * 256;
  float s = 0.f, sq = 0.f;
#pragma unroll
  for (int cc = 0; cc < CPG_; cc++) {
    float v = base[(size_t)cc * N_ + t];
    s += v; sq += v * v;
  }
#pragma unroll
  for (int off = 32; off; off >>= 1) {
    s  += __shfl_down(s,  off, 64);
    sq += __shfl_down(sq, off, 64);
  }
  int wave = t >> 6, lane = t & 63;
  if (lane == 0) { ls[wave * 2] = s; ls[wave * 2 + 1] = sq; }
  __syncthreads();
  if (t == 0) {
    float S = ls[0] + ls[2] + ls[4] + ls[6];
    float SQ = ls[1] + ls[3] + ls[5] + ls[7];
    partial[idx * 2] = S; partial[idx * 2 + 1] = SQ;
  }
}

// ---------------------------------------------------------------------------
// Kernel 2: normalize + transpose with INLINE stats. x -> hT (B,N,C) bf16.
// ---------------------------------------------------------------------------
__global__ void gn_apply(const float* __restrict__ x,
                         const float* __restrict__ nw, const float* __restrict__ nb,
                         const float* __restrict__ partial, unsigned short* __restrict__ hT) {
  int nt = blockIdx.x, ct = blockIdx.y, b = blockIdx.z;
  __shared__ unsigned short tile[32][72];
  int t = threadIdx.x;
  int lane = t & 63;
  int grp = b * G_ + ct;
  float s = 0.f, sq = 0.f;
  if (lane < 16) {
    s  = partial[(grp * 16 + lane) * 2];
    sq = partial[(grp * 16 + lane) * 2 + 1];
  }
#pragma unroll
  for (int off = 8; off; off >>= 1) {
    s  += __shfl_down(s,  off, 64);
    sq += __shfl_down(sq, off, 64);
  }
  s  = __shfl(s,  0, 64);
  sq = __shfl(sq, 0, 64);
  const float inv = 1.0f / (float)GRP_ELEMS;
  float mean = s * inv;
  float rstd = rsqrtf(sq * inv - mean * mean + 1e-5f);

  int n_loc = t & 63, c_loc = t >> 6;
  const float* xb = x + (size_t)(b * C_ + ct * CPG_) * N_ + nt * 64;
#pragma unroll
  for (int rr = 0; rr < 8; rr++) {
    int cc = rr * 4 + c_loc;
    int c = ct * CPG_ + cc;
    float v = xb[(size_t)cc * N_ + n_loc];
    v = (v - mean) * rstd * nw[c] + nb[c];
    tile[cc][n_loc] = f2bf(v);
  }
  __syncthreads();
  // packed write: thread handles n = t>>2, 8 consecutive c = (t&3)*8
  int n = t >> 2, c8 = (t & 3) * 8;
  us4 lo, hi;
#pragma unroll
  for (int j = 0; j < 4; j++) lo[j] = tile[c8 + j][n];
#pragma unroll
  for (int j = 0; j < 4; j++) hi[j] = tile[c8 + 4 + j][n];
  unsigned short* outp = hT + ((size_t)(b * N_ + nt * 64 + n)) * C_ + ct * CPG_ + c8;
  *reinterpret_cast<us4*>(outp) = lo;
  *reinterpret_cast<us4*>(outp + 4) = hi;
}

// ---------------------------------------------------------------------------
// Kernel 3: qkv GEMM, 128-n x 128-o blocks. grid 768 (1D XCD-affine).
// ---------------------------------------------------------------------------
__global__ __launch_bounds__(256) void qkv_gemm(
    const unsigned short* __restrict__ hT, const unsigned short* __restrict__ wq,
    const float* __restrict__ qb,
    unsigned short* __restrict__ Qt, unsigned short* __restrict__ Kt,
    unsigned short* __restrict__ V) {
  int ot = blockIdx.x >> 7;
  int nt = (blockIdx.x & 127) >> 2;
  int b  = blockIdx.x & 3;
  int t = threadIdx.x;
  int wave = t >> 6, lane = t & 63, l15 = lane & 15, quad = lane >> 4, l7 = l15 & 7;

  __shared__ __align__(16) unsigned short sh[128 * C_];
  {
    int row0 = wave * 2 + (lane >> 5);
    int col8 = lane & 31;
    int src8 = (col8 & 24) | ((col8 & 7) ^ (row0 & 7));
    const unsigned short* gsrc = hT + ((size_t)(b * N_ + nt * 128 + row0)) * C_ + src8 * 8;
#pragma unroll
    for (int it = 0; it < 16; it++)
      dma16(gsrc + (size_t)it * 8 * C_, sh + (it * 8 + wave * 2) * C_);
  }

  f32x4 acc[2][8];
#pragma unroll
  for (int r = 0; r < 2; r++)
#pragma unroll
    for (int tt = 0; tt < 8; tt++) acc[r][tt] = (f32x4){0.f, 0.f, 0.f, 0.f};

  const short8* arow[2];
#pragma unroll
  for (int r = 0; r < 2; r++)
    arow[r] = reinterpret_cast<const short8*>(
        wq + (size_t)(ot * 128 + wave * 32 + r * 16 + l15) * C_);

  asm volatile("s_waitcnt vmcnt(0)" ::: "memory");
  __syncthreads();

#pragma unroll
  for (int kk = 0; kk < 8; kk++) {
    int g = kk * 4 + quad;
    int col8 = (g & 24) | ((g & 7) ^ l7);
    short8 bfr[8];
#pragma unroll
    for (int tt = 0; tt < 8; tt++)
      bfr[tt] = *reinterpret_cast<const short8*>(&sh[(tt * 16 + l15) * C_ + col8 * 8]);
#pragma unroll
    for (int r = 0; r < 2; r++) {
      short8 a = arow[r][g];
#pragma unroll
      for (int tt = 0; tt < 8; tt++)
        acc[r][tt] = __builtin_amdgcn_mfma_f32_16x16x32_bf16(a, bfr[tt], acc[r][tt], 0, 0, 0);
    }
  }

  int sec = ot >> 1;                       // 0=Q, 1=K, 2=V
  int head = (ot & 1) * 2 + (wave >> 1);   // head index within batch
  int bh = b * NH_ + head;
  const float SC = 0.125f * 1.44269504088896340736f;  // 1/sqrt(hd) * log2(e)

#pragma unroll
  for (int r = 0; r < 2; r++) {
    int o_glob = ot * 128 + wave * 32 + r * 16;        // row base (bias index)
    int cw = (o_glob & 63) + quad * 4;                 // channel within head
    if (sec == 0) {
#pragma unroll
      for (int tt = 0; tt < 8; tt++) {
        int n = nt * 128 + tt * 16 + l15;
        us4 pk;
#pragma unroll
        for (int i = 0; i < 4; i++)
          pk[i] = f2bf((acc[r][tt][i] + qb[o_glob + quad * 4 + i]) * SC);
        *reinterpret_cast<us4*>(Qt + ((size_t)bh * N_ + n) * HD_ + cw) = pk;
      }
    } else if (sec == 1) {
#pragma unroll
      for (int tt = 0; tt < 8; tt++) {
        int n = nt * 128 + tt * 16 + l15;
        us4 pk;
#pragma unroll
        for (int i = 0; i < 4; i++)
          pk[i] = f2bf(acc[r][tt][i] + qb[o_glob + quad * 4 + i]);
        *reinterpret_cast<us4*>(Kt + ((size_t)bh * N_ + n) * HD_ + cw) = pk;
      }
    } else {
#pragma unroll
      for (int tt = 0; tt < 8; tt++) {
        int n = nt * 128 + tt * 16 + l15;
#pragma unroll
        for (int i = 0; i < 4; i++)
          V[((size_t)bh * HD_ + cw + i) * N_ + n] =
              f2bf(acc[r][tt][i] + qb[o_glob + quad * 4 + i]);
      }
    }
  }
}

// ---------------------------------------------------------------------------
// Kernel 4: flash attention (R12 structure + T5 setprio phase hinting).
// 4 waves = 2 qsub x 2 khalf; K+V LDS dbuf per khalf; in-register P
// quad-transpose; cross-wave merge epilogue.
// ---------------------------------------------------------------------------
__global__ __launch_bounds__(256, 2) void flash_attn(
    const unsigned short* __restrict__ Qt, const unsigned short* __restrict__ Kt,
    const unsigned short* __restrict__ Vv, unsigned short* __restrict__ aoT) {
  int bh = blockIdx.x & 15, qt = blockIdx.x >> 4;
  int b = bh >> 2, head = bh & 3;
  int t = threadIdx.x;
  int wave = t >> 6, lane = t & 63, l15 = lane & 15, quad = lane >> 4;
  int l7 = l15 & 7;
  int qsub = wave >> 1, khalf = wave & 1;

  const unsigned short* Qb = Qt + (size_t)bh * N_ * HD_;
  const unsigned short* Kb = Kt + (size_t)bh * N_ * HD_;
  const unsigned short* Vb = Vv + (size_t)bh * HD_ * N_;
  int q_base = qt * 128 + qsub * 64;

  __shared__ __align__(16) unsigned char smem[65536];
  unsigned short* Ks = (unsigned short*)smem;
  unsigned short* Vs = (unsigned short*)(smem + 32768);
  float* Obuf = (float*)smem;                 // epilogue reuse: qsub*4352 + c*68 + q
  float* lbuf = (float*)(smem + 34816);       // qsub*64 + q

  const short8 vones = {(short)0x3F80, (short)0x3F80, (short)0x3F80, (short)0x3F80,
                        (short)0x3F80, (short)0x3F80, (short)0x3F80, (short)0x3F80};
  const f32x4 fzero = (f32x4){0.f, 0.f, 0.f, 0.f};

  short8 qf[4][2];
#pragma unroll
  for (int r = 0; r < 4; r++)
#pragma unroll
    for (int h = 0; h < 2; h++)
      qf[r][h] = *reinterpret_cast<const short8*>(
          Qb + (size_t)(q_base + r * 16 + l15) * HD_ + h * 32 + quad * 8);

  f32x4 oa[4][4], la[4];
#pragma unroll
  for (int r = 0; r < 4; r++) {
    la[r] = (f32x4){0.f, 0.f, 0.f, 0.f};
#pragma unroll
    for (int ct = 0; ct < 4; ct++) oa[r][ct] = (f32x4){0.f, 0.f, 0.f, 0.f};
  }

  int i8 = lane >> 3, e = lane & 7;
  int perm = (e ^ i8) * 8;   // XOR swizzle of 8-element groups
  int kvoff = (khalf * 2) * 4096;
  auto stage = [&](int kt2, int buf) {
    int m0 = khalf * 2048 + kt2 * 64;
    unsigned short* Kd = Ks + kvoff + buf * 4096;
    unsigned short* Vd = Vs + kvoff + buf * 4096;
#pragma unroll
    for (int cc = 0; cc < 4; cc++) {
      int c = qsub * 4 + cc;
      dma16(Kb + (size_t)(m0 + c * 8 + i8) * HD_ + perm, Kd + c * 512);
      dma16(Vb + (size_t)(c * 8 + i8) * N_ + m0 + perm, Vd + c * 512);
    }
  };

  stage(0, 0);

#pragma unroll 1
  for (int kt = 0; kt < 32; kt++) {
    int buf = kt & 1;
    if (kt + 1 < 32) {
      stage(kt + 1, buf ^ 1);                          // issue prefetch first
      asm volatile("s_waitcnt vmcnt(8)" ::: "memory"); // wait only tile kt's 8
    } else {
      asm volatile("s_waitcnt vmcnt(0)" ::: "memory");
    }
    __builtin_amdgcn_s_barrier();
    __builtin_amdgcn_s_setprio(1);   // compute phase: favor this wave

    const unsigned short* Kbuf = Ks + kvoff + buf * 4096;
    const unsigned short* Vbuf = Vs + kvoff + buf * 4096;

    short8 kf[4][2], vf[4][2];
#pragma unroll
    for (int tt = 0; tt < 4; tt++)
#pragma unroll
      for (int kh2 = 0; kh2 < 2; kh2++) {
        kf[tt][kh2] = *reinterpret_cast<const short8*>(
            &Kbuf[(tt * 16 + l15) * 64 + (((kh2 * 4 + quad) ^ l7) * 8)]);
        vf[tt][kh2] = *reinterpret_cast<const short8*>(
            &Vbuf[(tt * 16 + l15) * 64 + (((kh2 * 4 + quad) ^ l7) * 8)]);
      }

#pragma unroll
    for (int r = 0; r < 4; r++) {
      f32x4 s[4];
#pragma unroll
      for (int tt = 0; tt < 4; tt++) {
        f32x4 z = __builtin_amdgcn_mfma_f32_16x16x32_bf16(kf[tt][0], qf[r][0], fzero, 0, 0, 0);
        s[tt] = __builtin_amdgcn_mfma_f32_16x16x32_bf16(kf[tt][1], qf[r][1], z, 0, 0, 0);
      }
      // exp2 + pack: lane holds P[key=tt*16+quad*4+i][q=l15] as bf16x2 words.
      unsigned Apk[4], Bpk[4];
#pragma unroll
      for (int tt = 0; tt < 4; tt++) {
        Apk[tt] = pkbf2(__builtin_amdgcn_exp2f(s[tt][0]), __builtin_amdgcn_exp2f(s[tt][1]));
        Bpk[tt] = pkbf2(__builtin_amdgcn_exp2f(s[tt][2]), __builtin_amdgcn_exp2f(s[tt][3]));
      }
      // 4x4 quad transpose (fixed l15): PV B-frag lane (l15,quad) needs
      // P[key=quad*8+j][q=l15] -> permlane32_swap (quad^2) + permlane16_swap
      // (quad^1).
      union { unsigned u[4]; short8 v; } f0, f1;
      {
        auto ua = __builtin_amdgcn_permlane32_swap(Apk[0], Apk[1], false, false);
        auto pa = __builtin_amdgcn_permlane16_swap(ua[0], ua[1], false, false);
        auto ub = __builtin_amdgcn_permlane32_swap(Bpk[0], Bpk[1], false, false);
        auto pb = __builtin_amdgcn_permlane16_swap(ub[0], ub[1], false, false);
        f0.u[0] = pa[0]; f0.u[1] = pb[0]; f0.u[2] = pa[1]; f0.u[3] = pb[1];
        auto uc = __builtin_amdgcn_permlane32_swap(Apk[2], Apk[3], false, false);
        auto pc = __builtin_amdgcn_permlane16_swap(uc[0], uc[1], false, false);
        auto ud = __builtin_amdgcn_permlane32_swap(Bpk[2], Bpk[3], false, false);
        auto pd = __builtin_amdgcn_permlane16_swap(ud[0], ud[1], false, false);
        f1.u[0] = pc[0]; f1.u[1] = pd[0]; f1.u[2] = pc[1]; f1.u[3] = pd[1];
      }
      short8 pf0 = f0.v, pf1 = f1.v;
#pragma unroll
      for (int ct = 0; ct < 4; ct++) {
        oa[r][ct] = __builtin_amdgcn_mfma_f32_16x16x32_bf16(vf[ct][0], pf0, oa[r][ct], 0, 0, 0);
        oa[r][ct] = __builtin_amdgcn_mfma_f32_16x16x32_bf16(vf[ct][1], pf1, oa[r][ct], 0, 0, 0);
      }
      la[r] = __builtin_amdgcn_mfma_f32_16x16x32_bf16(vones, pf0, la[r], 0, 0, 0);
      la[r] = __builtin_amdgcn_mfma_f32_16x16x32_bf16(vones, pf1, la[r], 0, 0, 0);
    }
    __builtin_amdgcn_s_setprio(0);   // staging phase next
  }

  // ---- merge the two key-halves (exact: plain add, no max-sub) ----
  __builtin_amdgcn_s_barrier();
  if (khalf == 1) {
#pragma unroll
    for (int r = 0; r < 4; r++) {
#pragma unroll
      for (int ct = 0; ct < 4; ct++)
#pragma unroll
        for (int i = 0; i < 4; i++)
          Obuf[qsub * 4352 + (ct * 16 + quad * 4 + i) * 68 + r * 16 + l15] = oa[r][ct][i];
      if (quad == 0) lbuf[qsub * 64 + r * 16 + l15] = la[r][0];
    }
  }
  __builtin_amdgcn_s_barrier();
  if (khalf == 0) {
#pragma unroll
    for (int r = 0; r < 4; r++) {
      float inv = 1.0f / (la[r][0] + lbuf[qsub * 64 + r * 16 + l15]);
      int n = q_base + r * 16 + l15;
#pragma unroll
      for (int ct = 0; ct < 4; ct++) {
        const float* ob = &Obuf[qsub * 4352 + (ct * 16 + quad * 4) * 68 + r * 16 + l15];
        union { unsigned u2[2]; us4 v; } w;
        w.u2[0] = pkbf2((oa[r][ct][0] + ob[0]) * inv, (oa[r][ct][1] + ob[68]) * inv);
        w.u2[1] = pkbf2((oa[r][ct][2] + ob[136]) * inv, (oa[r][ct][3] + ob[204]) * inv);
        *reinterpret_cast<us4*>(
            aoT + ((size_t)(b * N_ + n)) * C_ + head * HD_ + ct * 16 + quad * 4) = w.v;
      }
    }
  }
}

// ---------------------------------------------------------------------------
// Kernel 5: proj GEMM + bias + residual, 128-n tiles, 1D XCD-aware grid
// (512 blocks): idx = ot*128 + nt*4 + b.
// ---------------------------------------------------------------------------
__global__ __launch_bounds__(256) void proj_gemm(
    const unsigned short* __restrict__ aoT, const unsigned short* __restrict__ wp,
    const float* __restrict__ pb, const float* __restrict__ x,
    float* __restrict__ out) {
  int ot = blockIdx.x >> 7;
  int nt = (blockIdx.x & 127) >> 2;
  int b  = blockIdx.x & 3;
  int t = threadIdx.x;
  int wave = t >> 6, lane = t & 63, l15 = lane & 15, quad = lane >> 4, l7 = l15 & 7;
  int o_base = ot * 64 + wave * 16;

  __shared__ __align__(16) unsigned short sh[128 * C_];
  {
    int row0 = wave * 2 + (lane >> 5);
    int col8 = lane & 31;
    int src8 = (col8 & 24) | ((col8 & 7) ^ (row0 & 7));
    const unsigned short* gsrc = aoT + ((size_t)(b * N_ + nt * 128 + row0)) * C_ + src8 * 8;
#pragma unroll
    for (int it = 0; it < 16; it++)
      dma16(gsrc + (size_t)it * 8 * C_, sh + (it * 8 + wave * 2) * C_);
  }

  f32x4 acc[8];
#pragma unroll
  for (int tt = 0; tt < 8; tt++) acc[tt] = (f32x4){0.f, 0.f, 0.f, 0.f};

  const short8* arow = reinterpret_cast<const short8*>(wp + (size_t)(o_base + l15) * C_);

  asm volatile("s_waitcnt vmcnt(0)" ::: "memory");
  __syncthreads();

#pragma unroll
  for (int kk = 0; kk < 8; kk++) {
    short8 a = arow[kk * 4 + quad];
    int g = kk * 4 + quad;
    int col8 = (g & 24) | ((g & 7) ^ l7);
#pragma unroll
    for (int tt = 0; tt < 8; tt++) {
      short8 bf = *reinterpret_cast<const short8*>(&sh[(tt * 16 + l15) * C_ + col8 * 8]);
      acc[tt] = __builtin_amdgcn_mfma_f32_16x16x32_bf16(a, bf, acc[tt], 0, 0, 0);
    }
  }
#pragma unroll
  for (int tt = 0; tt < 8; tt++) {
    int n = nt * 128 + tt * 16 + l15;
#pragma unroll
    for (int i = 0; i < 4; i++) {
      int o = o_base + quad * 4 + i;
      size_t idx = ((size_t)(b * C_ + o)) * N_ + n;
      out[idx] = acc[tt][i] + pb[o] + x[idx];
    }
  }
}

// ---------------------------------------------------------------------------
extern "C" void kernel_launch(void* const* d_in, const int* in_sizes, int n_in,
                              void* d_out, int out_size, void* d_ws, size_t ws_size,
                              hipStream_t stream) {
  const float* x      = (const float*)d_in[0];
  const float* norm_w = (const float*)d_in[1];
  const float* norm_b = (const float*)d_in[2];
  const float* qkv_w  = (const float*)d_in[3];
  const float* qkv_b  = (const float*)d_in[4];
  const float* proj_w = (const float*)d_in[5];
  const float* proj_b = (const float*)d_in[6];
  float* out = (float*)d_out;

  char* ws = (char*)d_ws;
  size_t off = 0;
  auto alloc = [&](size_t bytes) { size_t o = off; off = (off + bytes + 255) & ~(size_t)255; return o; };
  size_t off_partial = alloc(512 * 2 * sizeof(float));
  size_t off_stats   = alloc(32 * 2 * sizeof(float));   // unused (layout stability)
  size_t off_wq      = alloc((size_t)768 * 256 * 2);
  size_t off_wp      = alloc((size_t)256 * 256 * 2);
  size_t off_hT      = alloc((size_t)B_ * N_ * C_ * 2);
  size_t off_Qt      = alloc((size_t)B_ * NH_ * N_ * HD_ * 2);
  size_t off_Kt      = alloc((size_t)B_ * NH_ * N_ * HD_ * 2);
  size_t off_V       = alloc((size_t)B_ * NH_ * HD_ * N_ * 2);
  size_t off_aoT     = alloc((size_t)B_ * N_ * C_ * 2);
  (void)off_stats;

  float* partial = (float*)(ws + off_partial);
  unsigned short* wq  = (unsigned short*)(ws + off_wq);
  unsigned short* wp  = (unsigned short*)(ws + off_wp);
  unsigned short* hT  = (unsigned short*)(ws + off_hT);
  unsigned short* Qt  = (unsigned short*)(ws + off_Qt);
  unsigned short* Kt  = (unsigned short*)(ws + off_Kt);
  unsigned short* V   = (unsigned short*)(ws + off_V);
  unsigned short* aoT = (unsigned short*)(ws + off_aoT);

  gn_partial_cvt<<<1280, 256, 0, stream>>>(x, partial, qkv_w, proj_w, wq, wp);
  gn_apply<<<dim3(64, 8, 4), 256, 0, stream>>>(x, norm_w, norm_b, partial, hT);
  qkv_gemm<<<768, 256, 0, stream>>>(hT, wq, qkv_b, Qt, Kt, V);
  flash_attn<<<512, 256, 0, stream>>>(Qt, Kt, V, aoT);
  proj_gemm<<<512, 256, 0, stream>>>(aoT, wp, proj_b, x, out);
}